// Round 2
// baseline (534.420 us; speedup 1.0000x reference)
//
#include <hip/hip_runtime.h>
#include <hip/hip_bf16.h>

#define N_NODES 100000
#define N_EDGES 1600000

typedef __bf16 bf16x8 __attribute__((ext_vector_type(8)));
typedef __bf16 bf16x4 __attribute__((ext_vector_type(4)));
typedef float  f32x4  __attribute__((ext_vector_type(4)));

// ---------------- preprocessing: counting sort of edges by dst ----------------

__global__ __launch_bounds__(1024) void zero_kernel(int* __restrict__ p, int n) {
  int i = blockIdx.x * blockDim.x + threadIdx.x;
  if (i < n) p[i] = 0;
}

__global__ __launch_bounds__(256) void hist_kernel(const int* __restrict__ dst,
                                                   int* __restrict__ cnt, int E) {
  int i = blockIdx.x * blockDim.x + threadIdx.x;
  if (i < E) atomicAdd(&cnt[dst[i]], 1);
}

__global__ __launch_bounds__(1024) void scan_a(const int* __restrict__ cnt,
                                               int* __restrict__ offs,
                                               int* __restrict__ bsum, int n) {
  __shared__ int tmp[1024];
  int t = threadIdx.x;
  int i = blockIdx.x * 1024 + t;
  int v = (i < n) ? cnt[i] : 0;
  int x = v;
  tmp[t] = x;
  __syncthreads();
  for (int d = 1; d < 1024; d <<= 1) {
    int y = (t >= d) ? tmp[t - d] : 0;
    __syncthreads();
    x += y;
    tmp[t] = x;
    __syncthreads();
  }
  if (i < n) offs[i] = x - v;          // block-local exclusive
  if (t == 1023) bsum[blockIdx.x] = x; // block total
}

__global__ __launch_bounds__(128) void scan_b(int* __restrict__ bsum, int nb) {
  __shared__ int tmp[128];
  int t = threadIdx.x;
  int v = (t < nb) ? bsum[t] : 0;
  int x = v;
  tmp[t] = x;
  __syncthreads();
  for (int d = 1; d < 128; d <<= 1) {
    int y = (t >= d) ? tmp[t - d] : 0;
    __syncthreads();
    x += y;
    tmp[t] = x;
    __syncthreads();
  }
  if (t < nb) bsum[t] = x - v;         // exclusive
}

__global__ __launch_bounds__(1024) void scan_c(int* __restrict__ offs,
                                               int* __restrict__ cursor,
                                               const int* __restrict__ bsum,
                                               int n, int E) {
  int i = blockIdx.x * 1024 + threadIdx.x;
  if (i < n) {
    int o = offs[i] + bsum[blockIdx.x];
    offs[i] = o;
    cursor[i] = o;
  }
  if (i == 0) offs[n] = E;
}

__global__ __launch_bounds__(256) void scatter_kernel(const int* __restrict__ src,
                                                      const int* __restrict__ dst,
                                                      int* __restrict__ cursor,
                                                      int* __restrict__ ssrc, int E) {
  int i = blockIdx.x * blockDim.x + threadIdx.x;
  if (i < E) {
    int d = dst[i];
    int pos = atomicAdd(&cursor[d], 1);
    ssrc[pos] = src[i];
  }
}

// -------- weight swizzle: W[128][256] (=[Wl|Wr]) -> MFMA B-fragment order --------
// Wout[((tile*4+c)*64 + lane)*8 + j] = W[c*32 + (lane>>4)*8 + j][tile*16 + (lane&15)]

__global__ __launch_bounds__(256) void wswz_kernel(const float* __restrict__ Wl,
                                                   const float* __restrict__ Wr,
                                                   __bf16* __restrict__ Wout) {
  int i = blockIdx.x * blockDim.x + threadIdx.x;  // 0..32767
  int j = i & 7;
  int lane = (i >> 3) & 63;
  int c = (i >> 9) & 3;
  int tile = i >> 11;
  int k = c * 32 + ((lane >> 4) * 8) + j;
  int col = tile * 16 + (lane & 15);
  float v = (col < 128) ? Wl[k * 128 + col] : Wr[k * 128 + (col - 128)];
  Wout[i] = (__bf16)v;
}

// ---------------- fused GEMM: [P | R] = A @ [Wl | Wr] (+bias on R) ----------------
// block: 64 rows x 256 cols, 4 waves (16 rows each), K=128, mfma 16x16x32 bf16
// NOTE: when A_IS_F32==false, A may alias R (bf16, same [M][128] layout): each
// block reads rows m0..m0+63 into LDS before __syncthreads and only this block
// writes R for those same rows afterwards — safe.

template <bool A_IS_F32>
__global__ __launch_bounds__(256) void gemm_kernel(const void* __restrict__ Aptr,
                                                   const __bf16* __restrict__ Wswz,
                                                   const float* __restrict__ bias,
                                                   __bf16* __restrict__ P,
                                                   __bf16* __restrict__ R, int M) {
  __shared__ __bf16 ldsA[64][136];  // 272B row stride: 16B-aligned fragments
  const int t = threadIdx.x;
  const int m0 = blockIdx.x * 64;

  if (A_IS_F32) {
    const float* A = (const float*)Aptr;
#pragma unroll
    for (int it = 0; it < 8; ++it) {
      int row = it * 8 + (t >> 5);
      int col = (t & 31) * 4;
      float4 v = make_float4(0.f, 0.f, 0.f, 0.f);
      if (m0 + row < M) v = *(const float4*)&A[(size_t)(m0 + row) * 128 + col];
      bf16x4 b;
      b.x = (__bf16)v.x; b.y = (__bf16)v.y; b.z = (__bf16)v.z; b.w = (__bf16)v.w;
      *(bf16x4*)&ldsA[row][col] = b;
    }
  } else {
    const __bf16* A = (const __bf16*)Aptr;
#pragma unroll
    for (int it = 0; it < 4; ++it) {
      int row = it * 16 + (t >> 4);
      int col = (t & 15) * 8;
      uint4 v = make_uint4(0u, 0u, 0u, 0u);
      if (m0 + row < M) v = *(const uint4*)&A[(size_t)(m0 + row) * 128 + col];
      *(uint4*)&ldsA[row][col] = v;
    }
  }
  __syncthreads();

  const int lane = t & 63;
  const int w = t >> 6;        // wave 0..3 -> rows w*16..w*16+15
  const int q = lane >> 4;     // quad
  const int s = lane & 15;

  f32x4 acc[16];
  f32x4 zero = {0.f, 0.f, 0.f, 0.f};
#pragma unroll
  for (int i = 0; i < 16; ++i) acc[i] = zero;

  const __bf16* arow = &ldsA[w * 16 + s][0];
#pragma unroll
  for (int c = 0; c < 4; ++c) {
    bf16x8 a = *(const bf16x8*)&arow[c * 32 + q * 8];  // A[m=s][k=c*32+q*8+j]
#pragma unroll
    for (int nt = 0; nt < 16; ++nt) {
      bf16x8 b = *(const bf16x8*)&Wswz[(size_t)(((nt * 4 + c) * 64) + lane) * 8];
      acc[nt] = __builtin_amdgcn_mfma_f32_16x16x32_bf16(a, b, acc[nt], 0, 0, 0);
    }
  }

  // C/D layout: col = s + nt*16, row = q*4 + r  (within wave's 16-row tile)
  const int rbase = m0 + w * 16 + q * 4;
#pragma unroll
  for (int nt = 0; nt < 16; ++nt) {
    int col = nt * 16 + s;
#pragma unroll
    for (int r = 0; r < 4; ++r) {
      int row = rbase + r;
      if (row < M) {
        float v = acc[nt][r];
        if (nt < 8) {
          P[(size_t)row * 128 + col] = (__bf16)v;
        } else {
          R[(size_t)row * 128 + (col - 128)] = (__bf16)(v + bias[col - 128]);
        }
      }
    }
  }
}

// ------------- aggregation: H = relu(mean_agg(P) + R); FINAL fuses heads -------------
// one wave per node; 4 edges/iter; 16-lane group g reads edge base+g's full bf16 row.
// When !FINAL, H aliases R (in-place): this wave reads its own R row before writing
// its H row; no other wave touches the row.

template <bool FINAL>
__global__ __launch_bounds__(256) void agg_kernel(
    const __bf16* __restrict__ P, const __bf16* R,
    const int* __restrict__ offs, const int* __restrict__ ssrc,
    __bf16* H, float* __restrict__ out,
    const float* __restrict__ Wp, const float* __restrict__ Wd,
    const float* __restrict__ bp, const float* __restrict__ bd, int n) {
  int wid = (int)((blockIdx.x * blockDim.x + threadIdx.x) >> 6);
  if (wid >= n) return;
  int lane = threadIdx.x & 63;
  int g = lane >> 4;
  int s = lane & 15;
  int start = offs[wid];
  int end = offs[wid + 1];

  float acc[8];
#pragma unroll
  for (int j = 0; j < 8; ++j) acc[j] = 0.f;

  const __bf16* Pb = P + (size_t)s * 8;
  for (int base = start; base < end; base += 4) {
    int e = base + g;
    if (e < end) {
      int sn = ssrc[e];
      bf16x8 v = *(const bf16x8*)(Pb + (size_t)sn * 128);
#pragma unroll
      for (int j = 0; j < 8; ++j) acc[j] += (float)v[j];
    }
  }
#pragma unroll
  for (int j = 0; j < 8; ++j) {
    acc[j] += __shfl_xor(acc[j], 16, 64);
    acc[j] += __shfl_xor(acc[j], 32, 64);
  }

  int deg = end - start;
  float inv = 1.0f / (float)(deg > 0 ? deg : 1);

  bf16x8 rv = *(const bf16x8*)&R[(size_t)wid * 128 + s * 8];
  float h[8];
#pragma unroll
  for (int j = 0; j < 8; ++j) {
    h[j] = fmaxf(acc[j] * inv + (float)rv[j], 0.f);
  }

  if (!FINAL) {
    if (lane < 16) {
      bf16x8 o;
#pragma unroll
      for (int j = 0; j < 8; ++j) o[j] = (__bf16)h[j];
      *(bf16x8*)&H[(size_t)wid * 128 + s * 8] = o;
    }
  } else {
    float p = 0.f, dd = 0.f;
#pragma unroll
    for (int j = 0; j < 8; ++j) {
      p += h[j] * Wp[s * 8 + j];
      dd += h[j] * Wd[s * 8 + j];
    }
    p += __shfl_xor(p, 1, 64);  p += __shfl_xor(p, 2, 64);
    p += __shfl_xor(p, 4, 64);  p += __shfl_xor(p, 8, 64);
    dd += __shfl_xor(dd, 1, 64); dd += __shfl_xor(dd, 2, 64);
    dd += __shfl_xor(dd, 4, 64); dd += __shfl_xor(dd, 8, 64);
    if (lane == 0) {
      float preds = p + bp[0];
      float sg = 1.0f / (1.0f + __expf(-(dd + bd[0])));
      out[wid] = preds - sg;
      out[n + wid] = preds + sg;
    }
  }
}

// ----------------------------------- launch -----------------------------------

extern "C" void kernel_launch(void* const* d_in, const int* in_sizes, int n_in,
                              void* d_out, int out_size, void* d_ws, size_t ws_size,
                              hipStream_t stream) {
  const float* x    = (const float*)d_in[0];
  const int*   ei   = (const int*)d_in[1];   // int32 per harness contract
  const float* Wl1 = (const float*)d_in[2];
  const float* Wr1 = (const float*)d_in[3];
  const float* b1  = (const float*)d_in[4];
  const float* Wl2 = (const float*)d_in[5];
  const float* Wr2 = (const float*)d_in[6];
  const float* b2  = (const float*)d_in[7];
  const float* Wp  = (const float*)d_in[8];
  const float* bp  = (const float*)d_in[9];
  const float* Wd  = (const float*)d_in[10];
  const float* bd  = (const float*)d_in[11];
  float* out = (float*)d_out;

  const int N = N_NODES, E = N_EDGES;
  const int* src = ei;
  const int* dst = ei + E;

  char* w = (char*)d_ws;
  __bf16* P    = (__bf16*)w; w += (size_t)N * 128 * 2;   // 25.6 MB (P1 then P2)
  __bf16* Rbuf = (__bf16*)w; w += (size_t)N * 128 * 2;   // 25.6 MB (R1 -> H1 -> R2)
  int* ssrc    = (int*)w;    w += (size_t)E * 4;         // 6.4 MB
  int* cnt     = (int*)w;    w += (size_t)N * 4;
  int* offs    = (int*)w;    w += (size_t)(N + 32) * 4;
  int* cursor  = (int*)w;    w += (size_t)N * 4;
  int* bsum    = (int*)w;    w += 512;
  __bf16* Ws1  = (__bf16*)w; w += 65536;
  __bf16* Ws2  = (__bf16*)w; w += 65536;

  const int NB = (N + 1023) / 1024;  // 98

  // graph preprocessing (shared by both layers)
  zero_kernel<<<NB, 1024, 0, stream>>>(cnt, N);
  wswz_kernel<<<128, 256, 0, stream>>>(Wl1, Wr1, Ws1);
  wswz_kernel<<<128, 256, 0, stream>>>(Wl2, Wr2, Ws2);
  hist_kernel<<<(E + 255) / 256, 256, 0, stream>>>(dst, cnt, E);
  scan_a<<<NB, 1024, 0, stream>>>(cnt, offs, bsum, N);
  scan_b<<<1, 128, 0, stream>>>(bsum, NB);
  scan_c<<<NB, 1024, 0, stream>>>(offs, cursor, bsum, N, E);
  scatter_kernel<<<(E + 255) / 256, 256, 0, stream>>>(src, dst, cursor, ssrc, E);

  const int GB = (N + 63) / 64;  // 1563
  // layer 1: P1 = x@Wl1, R1 = x@Wr1 + b1 ; H1 = relu(mean_agg(P1) + R1)  (H1 in Rbuf)
  gemm_kernel<true><<<GB, 256, 0, stream>>>(x, Ws1, b1, P, Rbuf, N);
  agg_kernel<false><<<(N + 3) / 4, 256, 0, stream>>>(P, Rbuf, offs, ssrc, Rbuf, nullptr,
                                                     nullptr, nullptr, nullptr, nullptr, N);
  // layer 2 + fused heads: P2 = H1@Wl2, R2 = H1@Wr2 + b2 (in place over H1)
  gemm_kernel<false><<<GB, 256, 0, stream>>>(Rbuf, Ws2, b2, P, Rbuf, N);
  agg_kernel<true><<<(N + 3) / 4, 256, 0, stream>>>(P, Rbuf, offs, ssrc, nullptr, out,
                                                    Wp, Wd, bp, bd, N);
}

// Round 3
// 381.600 us; speedup vs baseline: 1.4005x; 1.4005x over previous
//
#include <hip/hip_runtime.h>
#include <hip/hip_bf16.h>

#define N_NODES 100000
#define N_EDGES 1600000
#define NBUCK 391          // ceil(N_NODES / 256): bucket = 256-node dst range
#define BCAP 5120          // per-bucket capacity (expected 4096, sigma ~64)
#define ACHUNK 4096        // edges per partA block

typedef __bf16 bf16x8 __attribute__((ext_vector_type(8)));
typedef __bf16 bf16x4 __attribute__((ext_vector_type(4)));
typedef float  f32x4  __attribute__((ext_vector_type(4)));

// ---------------- preprocessing: 2-level radix partition of edges by dst ----------------

__global__ __launch_bounds__(512) void zerob_kernel(int* __restrict__ bcnt) {
  int t = threadIdx.x;
  if (t < NBUCK) bcnt[t] = 0;
}

// partA: partition edges into NBUCK bucket regions (bucket = dst >> 8).
// Per-block LDS histogram -> one global atomic per (block,bucket) -> dense streamed writes.
__global__ __launch_bounds__(256) void partA_kernel(const int* __restrict__ src,
                                                    const int* __restrict__ dst,
                                                    int* __restrict__ bcnt,
                                                    unsigned* __restrict__ packed, int E) {
  __shared__ int hist[NBUCK];
  __shared__ int curs[NBUCK];
  const int t = threadIdx.x;
  for (int i = t; i < NBUCK; i += 256) hist[i] = 0;
  __syncthreads();

  const int base = blockIdx.x * ACHUNK;
  const int lim = min(base + ACHUNK, E);

  int dloc[16], sloc[16];
  int myn = 0;
  for (int i = base + t; i < lim; i += 256) {
    dloc[myn] = dst[i];
    sloc[myn] = src[i];
    ++myn;
  }
  for (int k = 0; k < myn; ++k) atomicAdd(&hist[dloc[k] >> 8], 1);
  __syncthreads();

  for (int i = t; i < NBUCK; i += 256) {
    int h = hist[i];
    curs[i] = (h > 0) ? atomicAdd(&bcnt[i], h) : 0;
  }
  __syncthreads();

  for (int k = 0; k < myn; ++k) {
    int d = dloc[k];
    int b = d >> 8;
    int pos = atomicAdd(&curs[b], 1);
    if (pos < BCAP)
      packed[(size_t)b * BCAP + pos] = ((unsigned)sloc[k] << 8) | (unsigned)(d & 255);
  }
}

// bscan: exclusive scan of bucket counts -> bucket base offsets in ssrc; offs[N] = total.
__global__ __launch_bounds__(512) void bscan_kernel(const int* __restrict__ bcnt,
                                                    int* __restrict__ bbase,
                                                    int* __restrict__ offs, int N) {
  __shared__ int tmp[512];
  int t = threadIdx.x;
  int v = (t < NBUCK) ? min(bcnt[t], BCAP) : 0;
  int x = v;
  tmp[t] = x;
  __syncthreads();
  for (int d = 1; d < 512; d <<= 1) {
    int y = (t >= d) ? tmp[t - d] : 0;
    __syncthreads();
    x += y;
    tmp[t] = x;
    __syncthreads();
  }
  if (t < NBUCK) bbase[t] = x - v;
  if (t == NBUCK - 1) offs[N] = x;  // == E barring (statistically impossible) overflow
}

// partB: one block per bucket. LDS counting sort of <=BCAP edges over 256 local nodes;
// produces offs[] per node and dst-sorted ssrc[] (writes land in one contiguous region).
__global__ __launch_bounds__(256) void partB_kernel(const unsigned* __restrict__ packed,
                                                    const int* __restrict__ bcnt,
                                                    const int* __restrict__ bbase,
                                                    int* __restrict__ offs,
                                                    int* __restrict__ ssrc, int N) {
  __shared__ int hist[256];
  __shared__ int scanbuf[256];
  __shared__ int curs[256];
  const int b = blockIdx.x;
  const int t = threadIdx.x;
  const int nb = b * 256;
  const int ecnt = min(bcnt[b], BCAP);
  const int obase = bbase[b];
  const unsigned* pk = packed + (size_t)b * BCAP;

  hist[t] = 0;
  __syncthreads();

  unsigned ploc[20];
  int myn = 0;
  for (int i = t; i < ecnt; i += 256) {
    unsigned p = pk[i];
    ploc[myn++] = p;
    atomicAdd(&hist[p & 255u], 1);
  }
  __syncthreads();

  int v = hist[t];
  int x = v;
  scanbuf[t] = x;
  __syncthreads();
  for (int d = 1; d < 256; d <<= 1) {
    int y = (t >= d) ? scanbuf[t - d] : 0;
    __syncthreads();
    x += y;
    scanbuf[t] = x;
    __syncthreads();
  }
  int excl = x - v;
  if (nb + t < N) offs[nb + t] = obase + excl;
  curs[t] = excl;
  __syncthreads();

  for (int k = 0; k < myn; ++k) {
    unsigned p = ploc[k];
    int r = atomicAdd(&curs[p & 255u], 1);
    ssrc[obase + r] = (int)(p >> 8);
  }
}

// -------- weight swizzle: W[128][256] (=[Wl|Wr]) -> MFMA B-fragment order --------

__global__ __launch_bounds__(256) void wswz_kernel(const float* __restrict__ Wl,
                                                   const float* __restrict__ Wr,
                                                   __bf16* __restrict__ Wout) {
  int i = blockIdx.x * blockDim.x + threadIdx.x;  // 0..32767
  int j = i & 7;
  int lane = (i >> 3) & 63;
  int c = (i >> 9) & 3;
  int tile = i >> 11;
  int k = c * 32 + ((lane >> 4) * 8) + j;
  int col = tile * 16 + (lane & 15);
  float v = (col < 128) ? Wl[k * 128 + col] : Wr[k * 128 + (col - 128)];
  Wout[i] = (__bf16)v;
}

// ---------------- fused GEMM: [P | R] = A @ [Wl | Wr] (+bias on R) ----------------
// block: 64 rows x 256 cols, 4 waves (16 rows each), K=128, mfma 16x16x32 bf16
// When A_IS_F32==false, A may alias R: block reads rows m0..m0+63 into LDS before the
// barrier and only this block writes those same rows after it — safe.

template <bool A_IS_F32>
__global__ __launch_bounds__(256) void gemm_kernel(const void* __restrict__ Aptr,
                                                   const __bf16* __restrict__ Wswz,
                                                   const float* __restrict__ bias,
                                                   __bf16* __restrict__ P,
                                                   __bf16* __restrict__ R, int M) {
  __shared__ __bf16 ldsA[64][136];
  const int t = threadIdx.x;
  const int m0 = blockIdx.x * 64;

  if (A_IS_F32) {
    const float* A = (const float*)Aptr;
#pragma unroll
    for (int it = 0; it < 8; ++it) {
      int row = it * 8 + (t >> 5);
      int col = (t & 31) * 4;
      float4 v = make_float4(0.f, 0.f, 0.f, 0.f);
      if (m0 + row < M) v = *(const float4*)&A[(size_t)(m0 + row) * 128 + col];
      bf16x4 bv;
      bv.x = (__bf16)v.x; bv.y = (__bf16)v.y; bv.z = (__bf16)v.z; bv.w = (__bf16)v.w;
      *(bf16x4*)&ldsA[row][col] = bv;
    }
  } else {
    const __bf16* A = (const __bf16*)Aptr;
#pragma unroll
    for (int it = 0; it < 4; ++it) {
      int row = it * 16 + (t >> 4);
      int col = (t & 15) * 8;
      uint4 v = make_uint4(0u, 0u, 0u, 0u);
      if (m0 + row < M) v = *(const uint4*)&A[(size_t)(m0 + row) * 128 + col];
      *(uint4*)&ldsA[row][col] = v;
    }
  }
  __syncthreads();

  const int lane = t & 63;
  const int w = t >> 6;
  const int q = lane >> 4;
  const int s = lane & 15;

  f32x4 acc[16];
  f32x4 zero = {0.f, 0.f, 0.f, 0.f};
#pragma unroll
  for (int i = 0; i < 16; ++i) acc[i] = zero;

  const __bf16* arow = &ldsA[w * 16 + s][0];
#pragma unroll
  for (int c = 0; c < 4; ++c) {
    bf16x8 a = *(const bf16x8*)&arow[c * 32 + q * 8];
#pragma unroll
    for (int nt = 0; nt < 16; ++nt) {
      bf16x8 b = *(const bf16x8*)&Wswz[(size_t)(((nt * 4 + c) * 64) + lane) * 8];
      acc[nt] = __builtin_amdgcn_mfma_f32_16x16x32_bf16(a, b, acc[nt], 0, 0, 0);
    }
  }

  const int rbase = m0 + w * 16 + q * 4;
#pragma unroll
  for (int nt = 0; nt < 16; ++nt) {
    int col = nt * 16 + s;
#pragma unroll
    for (int r = 0; r < 4; ++r) {
      int row = rbase + r;
      if (row < M) {
        float v = acc[nt][r];
        if (nt < 8) {
          P[(size_t)row * 128 + col] = (__bf16)v;
        } else {
          R[(size_t)row * 128 + (col - 128)] = (__bf16)(v + bias[col - 128]);
        }
      }
    }
  }
}

// ------------- aggregation: H = relu(mean_agg(P) + R); FINAL fuses heads -------------
// one wave per node; 8 edges in flight (2 per 16-lane group) for MLP.
// When !FINAL, H aliases R in place (wave-private row).

template <bool FINAL>
__global__ __launch_bounds__(256) void agg_kernel(
    const __bf16* __restrict__ P, const __bf16* R,
    const int* __restrict__ offs, const int* __restrict__ ssrc,
    __bf16* H, float* __restrict__ out,
    const float* __restrict__ Wp, const float* __restrict__ Wd,
    const float* __restrict__ bp, const float* __restrict__ bd, int n) {
  int wid = (int)((blockIdx.x * blockDim.x + threadIdx.x) >> 6);
  if (wid >= n) return;
  int lane = threadIdx.x & 63;
  int g = lane >> 4;
  int s = lane & 15;
  int start = offs[wid];
  int end = offs[wid + 1];

  float acc[8];
#pragma unroll
  for (int j = 0; j < 8; ++j) acc[j] = 0.f;

  const __bf16* Pb = P + (size_t)s * 8;
  for (int base = start; base < end; base += 8) {
    int e0 = base + g;
    int e1 = base + 4 + g;
    if (e1 < end) {
      int sn0 = ssrc[e0];
      int sn1 = ssrc[e1];
      bf16x8 v0 = *(const bf16x8*)(Pb + (size_t)sn0 * 128);
      bf16x8 v1 = *(const bf16x8*)(Pb + (size_t)sn1 * 128);
#pragma unroll
      for (int j = 0; j < 8; ++j) acc[j] += (float)v0[j] + (float)v1[j];
    } else if (e0 < end) {
      int sn0 = ssrc[e0];
      bf16x8 v0 = *(const bf16x8*)(Pb + (size_t)sn0 * 128);
#pragma unroll
      for (int j = 0; j < 8; ++j) acc[j] += (float)v0[j];
    }
  }
#pragma unroll
  for (int j = 0; j < 8; ++j) {
    acc[j] += __shfl_xor(acc[j], 16, 64);
    acc[j] += __shfl_xor(acc[j], 32, 64);
  }

  int deg = end - start;
  float inv = 1.0f / (float)(deg > 0 ? deg : 1);

  bf16x8 rv = *(const bf16x8*)&R[(size_t)wid * 128 + s * 8];
  float h[8];
#pragma unroll
  for (int j = 0; j < 8; ++j) {
    h[j] = fmaxf(acc[j] * inv + (float)rv[j], 0.f);
  }

  if (!FINAL) {
    if (lane < 16) {
      bf16x8 o;
#pragma unroll
      for (int j = 0; j < 8; ++j) o[j] = (__bf16)h[j];
      *(bf16x8*)&H[(size_t)wid * 128 + s * 8] = o;
    }
  } else {
    float p = 0.f, dd = 0.f;
#pragma unroll
    for (int j = 0; j < 8; ++j) {
      p += h[j] * Wp[s * 8 + j];
      dd += h[j] * Wd[s * 8 + j];
    }
    p += __shfl_xor(p, 1, 64);  p += __shfl_xor(p, 2, 64);
    p += __shfl_xor(p, 4, 64);  p += __shfl_xor(p, 8, 64);
    dd += __shfl_xor(dd, 1, 64); dd += __shfl_xor(dd, 2, 64);
    dd += __shfl_xor(dd, 4, 64); dd += __shfl_xor(dd, 8, 64);
    if (lane == 0) {
      float preds = p + bp[0];
      float sg = 1.0f / (1.0f + __expf(-(dd + bd[0])));
      out[wid] = preds - sg;
      out[n + wid] = preds + sg;
    }
  }
}

// ----------------------------------- launch -----------------------------------

extern "C" void kernel_launch(void* const* d_in, const int* in_sizes, int n_in,
                              void* d_out, int out_size, void* d_ws, size_t ws_size,
                              hipStream_t stream) {
  const float* x    = (const float*)d_in[0];
  const int*   ei   = (const int*)d_in[1];   // int32 per harness contract
  const float* Wl1 = (const float*)d_in[2];
  const float* Wr1 = (const float*)d_in[3];
  const float* b1  = (const float*)d_in[4];
  const float* Wl2 = (const float*)d_in[5];
  const float* Wr2 = (const float*)d_in[6];
  const float* b2  = (const float*)d_in[7];
  const float* Wp  = (const float*)d_in[8];
  const float* bp  = (const float*)d_in[9];
  const float* Wd  = (const float*)d_in[10];
  const float* bd  = (const float*)d_in[11];
  float* out = (float*)d_out;

  const int N = N_NODES, E = N_EDGES;
  const int* src = ei;
  const int* dst = ei + E;

  char* w = (char*)d_ws;
  __bf16* P      = (__bf16*)w;   w += (size_t)N * 128 * 2;        // 25.6 MB
  __bf16* Rbuf   = (__bf16*)w;   w += (size_t)N * 128 * 2;        // 25.6 MB (R1->H1->R2)
  int* ssrc      = (int*)w;      w += (size_t)E * 4;              // 6.4 MB
  unsigned* pck  = (unsigned*)w; w += (size_t)NBUCK * BCAP * 4;   // 8.0 MB
  int* bcnt      = (int*)w;      w += 512 * 4;
  int* bbase     = (int*)w;      w += 512 * 4;
  int* offs      = (int*)w;      w += (size_t)(N + 32) * 4;
  __bf16* Ws1    = (__bf16*)w;   w += 65536;
  __bf16* Ws2    = (__bf16*)w;   w += 65536;

  // graph preprocessing (shared by both layers)
  zerob_kernel<<<1, 512, 0, stream>>>(bcnt);
  wswz_kernel<<<128, 256, 0, stream>>>(Wl1, Wr1, Ws1);
  wswz_kernel<<<128, 256, 0, stream>>>(Wl2, Wr2, Ws2);
  partA_kernel<<<(E + ACHUNK - 1) / ACHUNK, 256, 0, stream>>>(src, dst, bcnt, pck, E);
  bscan_kernel<<<1, 512, 0, stream>>>(bcnt, bbase, offs, N);
  partB_kernel<<<NBUCK, 256, 0, stream>>>(pck, bcnt, bbase, offs, ssrc, N);

  const int GB = (N + 63) / 64;  // 1563
  // layer 1: P1 = x@Wl1, R1 = x@Wr1 + b1 ; H1 = relu(mean_agg(P1) + R1)  (H1 in Rbuf)
  gemm_kernel<true><<<GB, 256, 0, stream>>>(x, Ws1, b1, P, Rbuf, N);
  agg_kernel<false><<<(N + 3) / 4, 256, 0, stream>>>(P, Rbuf, offs, ssrc, Rbuf, nullptr,
                                                     nullptr, nullptr, nullptr, nullptr, N);
  // layer 2 + fused heads: P2 = H1@Wl2, R2 = H1@Wr2 + b2 (in place over H1)
  gemm_kernel<false><<<GB, 256, 0, stream>>>(Rbuf, Ws2, b2, P, Rbuf, N);
  agg_kernel<true><<<(N + 3) / 4, 256, 0, stream>>>(P, Rbuf, offs, ssrc, nullptr, out,
                                                    Wp, Wd, bp, bd, N);
}

// Round 4
// 333.509 us; speedup vs baseline: 1.6024x; 1.1442x over previous
//
#include <hip/hip_runtime.h>
#include <hip/hip_bf16.h>

#define N_NODES 100000
#define N_EDGES 1600000
#define NBUCK 391          // ceil(N_NODES / 256): bucket = 256-node dst range
#define BCAP 5120          // per-bucket capacity (expected 4096, sigma ~64)
#define ACHUNK 4096        // edges per partA block

typedef __bf16 bf16x8 __attribute__((ext_vector_type(8)));
typedef __bf16 bf16x4 __attribute__((ext_vector_type(4)));
typedef float  f32x4  __attribute__((ext_vector_type(4)));
typedef float  f32x2  __attribute__((ext_vector_type(2)));

// Feature permutation for P/R/H rows: feature f lives at byte/elem position
// pos(f) = (f&15)*8 + (f>>4). Inverse: f(pos) = ((pos&7)<<4) | (pos>>3).
// This makes GEMM-epilogue per-thread stores contiguous AND agg per-lane reads
// contiguous. Layer-2 weight swizzle + head weights absorb the permutation.

// ---------------- preprocessing: 2-level radix partition of edges by dst ----------------

__global__ __launch_bounds__(512) void zerob_kernel(int* __restrict__ bcnt) {
  int t = threadIdx.x;
  if (t < NBUCK) bcnt[t] = 0;
}

__global__ __launch_bounds__(256) void partA_kernel(const int* __restrict__ src,
                                                    const int* __restrict__ dst,
                                                    int* __restrict__ bcnt,
                                                    unsigned* __restrict__ packed, int E) {
  __shared__ int hist[NBUCK];
  __shared__ int curs[NBUCK];
  const int t = threadIdx.x;
  for (int i = t; i < NBUCK; i += 256) hist[i] = 0;
  __syncthreads();

  const int base = blockIdx.x * ACHUNK;
  const int lim = min(base + ACHUNK, E);

  int dloc[16], sloc[16];
  int myn = 0;
  for (int i = base + t; i < lim; i += 256) {
    dloc[myn] = dst[i];
    sloc[myn] = src[i];
    ++myn;
  }
  for (int k = 0; k < myn; ++k) atomicAdd(&hist[dloc[k] >> 8], 1);
  __syncthreads();

  for (int i = t; i < NBUCK; i += 256) {
    int h = hist[i];
    curs[i] = (h > 0) ? atomicAdd(&bcnt[i], h) : 0;
  }
  __syncthreads();

  for (int k = 0; k < myn; ++k) {
    int d = dloc[k];
    int b = d >> 8;
    int pos = atomicAdd(&curs[b], 1);
    if (pos < BCAP)
      packed[(size_t)b * BCAP + pos] = ((unsigned)sloc[k] << 8) | (unsigned)(d & 255);
  }
}

__global__ __launch_bounds__(512) void bscan_kernel(const int* __restrict__ bcnt,
                                                    int* __restrict__ bbase,
                                                    int* __restrict__ offs, int N) {
  __shared__ int tmp[512];
  int t = threadIdx.x;
  int v = (t < NBUCK) ? min(bcnt[t], BCAP) : 0;
  int x = v;
  tmp[t] = x;
  __syncthreads();
  for (int d = 1; d < 512; d <<= 1) {
    int y = (t >= d) ? tmp[t - d] : 0;
    __syncthreads();
    x += y;
    tmp[t] = x;
    __syncthreads();
  }
  if (t < NBUCK) bbase[t] = x - v;
  if (t == NBUCK - 1) offs[N] = x;
}

__global__ __launch_bounds__(256) void partB_kernel(const unsigned* __restrict__ packed,
                                                    const int* __restrict__ bcnt,
                                                    const int* __restrict__ bbase,
                                                    int* __restrict__ offs,
                                                    int* __restrict__ ssrc, int N) {
  __shared__ int hist[256];
  __shared__ int scanbuf[256];
  __shared__ int curs[256];
  const int b = blockIdx.x;
  const int t = threadIdx.x;
  const int nb = b * 256;
  const int ecnt = min(bcnt[b], BCAP);
  const int obase = bbase[b];
  const unsigned* pk = packed + (size_t)b * BCAP;

  hist[t] = 0;
  __syncthreads();

  unsigned ploc[20];
  int myn = 0;
  for (int i = t; i < ecnt; i += 256) {
    unsigned p = pk[i];
    ploc[myn++] = p;
    atomicAdd(&hist[p & 255u], 1);
  }
  __syncthreads();

  int v = hist[t];
  int x = v;
  scanbuf[t] = x;
  __syncthreads();
  for (int d = 1; d < 256; d <<= 1) {
    int y = (t >= d) ? scanbuf[t - d] : 0;
    __syncthreads();
    x += y;
    scanbuf[t] = x;
    __syncthreads();
  }
  int excl = x - v;
  if (nb + t < N) offs[nb + t] = obase + excl;
  curs[t] = excl;
  __syncthreads();

  for (int k = 0; k < myn; ++k) {
    unsigned p = ploc[k];
    int r = atomicAdd(&curs[p & 255u], 1);
    ssrc[obase + r] = (int)(p >> 8);
  }
}

// -------- weight swizzle: W[128][256] (=[Wl|Wr]) -> MFMA B-fragment order --------
// Layer 2 additionally permutes input rows: position k reads feature f(k).

__global__ __launch_bounds__(256) void wswz_kernel(const float* __restrict__ Wl1,
                                                   const float* __restrict__ Wr1,
                                                   const float* __restrict__ Wl2,
                                                   const float* __restrict__ Wr2,
                                                   __bf16* __restrict__ W1out,
                                                   __bf16* __restrict__ W2out) {
  int gi = blockIdx.x * blockDim.x + threadIdx.x;  // 0..65535
  bool L2 = gi >= 32768;
  int i = gi & 32767;
  int j = i & 7;
  int lane = (i >> 3) & 63;
  int c = (i >> 9) & 3;
  int tile = i >> 11;
  int k = c * 32 + ((lane >> 4) * 8) + j;          // K position
  int krow = L2 ? (((k & 7) << 4) | (k >> 3)) : k; // feature row for this position
  int col = tile * 16 + (lane & 15);
  const float* Wl = L2 ? Wl2 : Wl1;
  const float* Wr = L2 ? Wr2 : Wr1;
  float v = (col < 128) ? Wl[krow * 128 + col] : Wr[krow * 128 + (col - 128)];
  (L2 ? W2out : W1out)[i] = (__bf16)v;
}

// ---------------- fused GEMM: [P | R] = A @ [Wl | Wr] (+bias on R) ----------------
// block: 64 rows x 256 cols, 4 waves, K=128, mfma 16x16x32 bf16.
// P: fp8 e4m3, permuted layout. R: bf16, permuted layout. A may alias R (in-place).

template <bool A_IS_F32>
__global__ __launch_bounds__(256) void gemm_kernel(const void* __restrict__ Aptr,
                                                   const __bf16* __restrict__ Wswz,
                                                   const float* __restrict__ bias,
                                                   unsigned char* __restrict__ P,
                                                   __bf16* __restrict__ R, int M) {
  __shared__ __bf16 ldsA[64][136];
  const int t = threadIdx.x;
  const int m0 = blockIdx.x * 64;

  if (A_IS_F32) {
    const float* A = (const float*)Aptr;
#pragma unroll
    for (int it = 0; it < 8; ++it) {
      int row = it * 8 + (t >> 5);
      int col = (t & 31) * 4;
      float4 v = make_float4(0.f, 0.f, 0.f, 0.f);
      if (m0 + row < M) v = *(const float4*)&A[(size_t)(m0 + row) * 128 + col];
      bf16x4 bv;
      bv.x = (__bf16)v.x; bv.y = (__bf16)v.y; bv.z = (__bf16)v.z; bv.w = (__bf16)v.w;
      *(bf16x4*)&ldsA[row][col] = bv;
    }
  } else {
    const __bf16* A = (const __bf16*)Aptr;
#pragma unroll
    for (int it = 0; it < 4; ++it) {
      int row = it * 16 + (t >> 4);
      int col = (t & 15) * 8;
      uint4 v = make_uint4(0u, 0u, 0u, 0u);
      if (m0 + row < M) v = *(const uint4*)&A[(size_t)(m0 + row) * 128 + col];
      *(uint4*)&ldsA[row][col] = v;
    }
  }

  const int lane = t & 63;
  const int w = t >> 6;
  const int q = lane >> 4;
  const int s = lane & 15;

  // per-lane bias for R features 16j+s
  float breg[8];
#pragma unroll
  for (int j = 0; j < 8; ++j) breg[j] = bias[j * 16 + s];

  __syncthreads();

  f32x4 acc[16];
  f32x4 zero = {0.f, 0.f, 0.f, 0.f};
#pragma unroll
  for (int i = 0; i < 16; ++i) acc[i] = zero;

  const __bf16* arow = &ldsA[w * 16 + s][0];
#pragma unroll
  for (int c = 0; c < 4; ++c) {
    bf16x8 a = *(const bf16x8*)&arow[c * 32 + q * 8];
#pragma unroll
    for (int nt = 0; nt < 16; ++nt) {
      bf16x8 b = *(const bf16x8*)&Wswz[(size_t)(((nt * 4 + c) * 64) + lane) * 8];
      acc[nt] = __builtin_amdgcn_mfma_f32_16x16x32_bf16(a, b, acc[nt], 0, 0, 0);
    }
  }

  // C/D: col = nt*16 + s, row = q*4 + r. Store permuted: feature nt*16+s -> pos s*8+nt.
  const int rbase = m0 + w * 16 + q * 4;
#pragma unroll
  for (int r = 0; r < 4; ++r) {
    int row = rbase + r;
    if (row < M) {
      unsigned lo = 0, hi = 0;
      lo = __builtin_amdgcn_cvt_pk_fp8_f32(acc[0][r], acc[1][r], lo, false);
      lo = __builtin_amdgcn_cvt_pk_fp8_f32(acc[2][r], acc[3][r], lo, true);
      hi = __builtin_amdgcn_cvt_pk_fp8_f32(acc[4][r], acc[5][r], hi, false);
      hi = __builtin_amdgcn_cvt_pk_fp8_f32(acc[6][r], acc[7][r], hi, true);
      uint2 pv; pv.x = lo; pv.y = hi;
      *(uint2*)&P[(size_t)row * 128 + s * 8] = pv;

      bf16x8 o;
#pragma unroll
      for (int j = 0; j < 8; ++j) o[j] = (__bf16)(acc[8 + j][r] + breg[j]);
      *(bf16x8*)&R[(size_t)row * 128 + s * 8] = o;
    }
  }
}

// ------------- aggregation: H = relu(mean_agg(P) + R); FINAL fuses heads -------------
// one wave per node; 16 edges in flight (4 per 16-lane group); fp8 rows (128 B).
// Lane s's 8 accumulated values are features {16j+s, j=0..7} (permuted layout).

template <bool FINAL>
__global__ __launch_bounds__(256) void agg_kernel(
    const unsigned char* __restrict__ P, const __bf16* R,
    const int* __restrict__ offs, const int* __restrict__ ssrc,
    __bf16* H, float* __restrict__ out,
    const float* __restrict__ Wp, const float* __restrict__ Wd,
    const float* __restrict__ bp, const float* __restrict__ bd, int n) {
  int wid = (int)((blockIdx.x * blockDim.x + threadIdx.x) >> 6);
  if (wid >= n) return;
  int lane = threadIdx.x & 63;
  int g = lane >> 4;
  int s = lane & 15;
  int start = offs[wid];
  int end = offs[wid + 1];

  f32x2 a01 = {0.f, 0.f}, a23 = {0.f, 0.f}, a45 = {0.f, 0.f}, a67 = {0.f, 0.f};

  const unsigned char* Pb = P + (size_t)s * 8;
  for (int base = start; base < end; base += 16) {
#pragma unroll
    for (int k = 0; k < 4; ++k) {
      int e = base + k * 4 + g;
      if (e < end) {
        int sn = ssrc[e];
        uint2 v = *(const uint2*)(Pb + (size_t)sn * 128);
        a01 += __builtin_amdgcn_cvt_pk_f32_fp8(v.x, false);
        a23 += __builtin_amdgcn_cvt_pk_f32_fp8(v.x, true);
        a45 += __builtin_amdgcn_cvt_pk_f32_fp8(v.y, false);
        a67 += __builtin_amdgcn_cvt_pk_f32_fp8(v.y, true);
      }
    }
  }

  float acc[8] = {a01[0], a01[1], a23[0], a23[1], a45[0], a45[1], a67[0], a67[1]};
#pragma unroll
  for (int j = 0; j < 8; ++j) {
    acc[j] += __shfl_xor(acc[j], 16, 64);
    acc[j] += __shfl_xor(acc[j], 32, 64);
  }

  int deg = end - start;
  float inv = 1.0f / (float)(deg > 0 ? deg : 1);

  bf16x8 rv = *(const bf16x8*)&R[(size_t)wid * 128 + s * 8];
  float h[8];
#pragma unroll
  for (int j = 0; j < 8; ++j) {
    h[j] = fmaxf(acc[j] * inv + (float)rv[j], 0.f);
  }

  if (!FINAL) {
    if (lane < 16) {
      bf16x8 o;
#pragma unroll
      for (int j = 0; j < 8; ++j) o[j] = (__bf16)h[j];
      *(bf16x8*)&H[(size_t)wid * 128 + s * 8] = o;
    }
  } else {
    float p = 0.f, dd = 0.f;
#pragma unroll
    for (int j = 0; j < 8; ++j) {
      float wp = Wp[j * 16 + s];
      float wd = Wd[j * 16 + s];
      p += h[j] * wp;
      dd += h[j] * wd;
    }
    p += __shfl_xor(p, 1, 64);  p += __shfl_xor(p, 2, 64);
    p += __shfl_xor(p, 4, 64);  p += __shfl_xor(p, 8, 64);
    dd += __shfl_xor(dd, 1, 64); dd += __shfl_xor(dd, 2, 64);
    dd += __shfl_xor(dd, 4, 64); dd += __shfl_xor(dd, 8, 64);
    if (lane == 0) {
      float preds = p + bp[0];
      float sg = 1.0f / (1.0f + __expf(-(dd + bd[0])));
      out[wid] = preds - sg;
      out[n + wid] = preds + sg;
    }
  }
}

// ----------------------------------- launch -----------------------------------

extern "C" void kernel_launch(void* const* d_in, const int* in_sizes, int n_in,
                              void* d_out, int out_size, void* d_ws, size_t ws_size,
                              hipStream_t stream) {
  const float* x    = (const float*)d_in[0];
  const int*   ei   = (const int*)d_in[1];   // int32 per harness contract
  const float* Wl1 = (const float*)d_in[2];
  const float* Wr1 = (const float*)d_in[3];
  const float* b1  = (const float*)d_in[4];
  const float* Wl2 = (const float*)d_in[5];
  const float* Wr2 = (const float*)d_in[6];
  const float* b2  = (const float*)d_in[7];
  const float* Wp  = (const float*)d_in[8];
  const float* bp  = (const float*)d_in[9];
  const float* Wd  = (const float*)d_in[10];
  const float* bd  = (const float*)d_in[11];
  float* out = (float*)d_out;

  const int N = N_NODES, E = N_EDGES;
  const int* src = ei;
  const int* dst = ei + E;

  char* w = (char*)d_ws;
  unsigned char* P = (unsigned char*)w; w += (size_t)N * 128;     // 12.8 MB fp8
  __bf16* Rbuf   = (__bf16*)w;   w += (size_t)N * 128 * 2;        // 25.6 MB (R1->H1->R2)
  int* ssrc      = (int*)w;      w += (size_t)E * 4;              // 6.4 MB
  unsigned* pck  = (unsigned*)w; w += (size_t)NBUCK * BCAP * 4;   // 8.0 MB
  int* bcnt      = (int*)w;      w += 512 * 4;
  int* bbase     = (int*)w;      w += 512 * 4;
  int* offs      = (int*)w;      w += (size_t)(N + 32) * 4;
  __bf16* Ws1    = (__bf16*)w;   w += 65536;
  __bf16* Ws2    = (__bf16*)w;   w += 65536;

  // graph preprocessing (shared by both layers)
  zerob_kernel<<<1, 512, 0, stream>>>(bcnt);
  wswz_kernel<<<256, 256, 0, stream>>>(Wl1, Wr1, Wl2, Wr2, Ws1, Ws2);
  partA_kernel<<<(E + ACHUNK - 1) / ACHUNK, 256, 0, stream>>>(src, dst, bcnt, pck, E);
  bscan_kernel<<<1, 512, 0, stream>>>(bcnt, bbase, offs, N);
  partB_kernel<<<NBUCK, 256, 0, stream>>>(pck, bcnt, bbase, offs, ssrc, N);

  const int GB = (N + 63) / 64;  // 1563
  // layer 1: P1 = x@Wl1 (fp8), R1 = x@Wr1 + b1 ; H1 = relu(mean_agg(P1) + R1) in Rbuf
  gemm_kernel<true><<<GB, 256, 0, stream>>>(x, Ws1, b1, P, Rbuf, N);
  agg_kernel<false><<<(N + 3) / 4, 256, 0, stream>>>(P, Rbuf, offs, ssrc, Rbuf, nullptr,
                                                     nullptr, nullptr, nullptr, nullptr, N);
  // layer 2 + fused heads: P2 = H1@Wl2 (fp8), R2 = H1@Wr2 + b2 (in place over H1)
  gemm_kernel<false><<<GB, 256, 0, stream>>>(Rbuf, Ws2, b2, P, Rbuf, N);
  agg_kernel<true><<<(N + 3) / 4, 256, 0, stream>>>(P, Rbuf, offs, ssrc, nullptr, out,
                                                    Wp, Wd, bp, bd, N);
}

// Round 5
// 275.798 us; speedup vs baseline: 1.9377x; 1.2092x over previous
//
#include <hip/hip_runtime.h>
#include <hip/hip_bf16.h>

#define N_NODES 100000
#define N_EDGES 1600000
#define NBUCK 391          // ceil(N_NODES / 256): bucket = 256-node dst range
#define BCAP 5120          // per-bucket capacity (expected 4096, sigma ~64)
#define ACHUNK 4096        // edges per partA block

typedef __bf16 bf16x8 __attribute__((ext_vector_type(8)));
typedef __bf16 bf16x4 __attribute__((ext_vector_type(4)));
typedef float  f32x4  __attribute__((ext_vector_type(4)));
typedef float  f32x2  __attribute__((ext_vector_type(2)));

// Feature permutation for P/R/H rows: feature f lives at position
// pos(f) = (f&15)*8 + (f>>4). Layer-2 weight swizzle + head weights absorb it.
// P has N+1 rows: row N is an all-zero sentinel row for padded edge slots.

// ---------------- preprocessing: 2-level radix partition of edges by dst ----------------

__global__ __launch_bounds__(512) void zerob_kernel(int* __restrict__ bcnt,
                                                    int* __restrict__ Psent) {
  int t = threadIdx.x;
  if (t < NBUCK) bcnt[t] = 0;
  if (t >= 480) Psent[t - 480] = 0;   // 32 dwords = 128 B = fp8 row N of P
}

__global__ __launch_bounds__(256) void partA_kernel(const int* __restrict__ src,
                                                    const int* __restrict__ dst,
                                                    int* __restrict__ bcnt,
                                                    unsigned* __restrict__ packed, int E) {
  __shared__ int hist[NBUCK];
  __shared__ int curs[NBUCK];
  const int t = threadIdx.x;
  for (int i = t; i < NBUCK; i += 256) hist[i] = 0;
  __syncthreads();

  const int base = blockIdx.x * ACHUNK;
  const int lim = min(base + ACHUNK, E);

  int dloc[16], sloc[16];
  int myn = 0;
  for (int i = base + t; i < lim; i += 256) {
    dloc[myn] = dst[i];
    sloc[myn] = src[i];
    ++myn;
  }
  for (int k = 0; k < myn; ++k) atomicAdd(&hist[dloc[k] >> 8], 1);
  __syncthreads();

  for (int i = t; i < NBUCK; i += 256) {
    int h = hist[i];
    curs[i] = (h > 0) ? atomicAdd(&bcnt[i], h) : 0;
  }
  __syncthreads();

  for (int k = 0; k < myn; ++k) {
    int d = dloc[k];
    int b = d >> 8;
    int pos = atomicAdd(&curs[b], 1);
    if (pos < BCAP)
      packed[(size_t)b * BCAP + pos] = ((unsigned)sloc[k] << 8) | (unsigned)(d & 255);
  }
}

// partBh: per-bucket per-node histogram -> true deg, padded count (mult of 4),
// and per-bucket padded total.
__global__ __launch_bounds__(256) void partBh_kernel(const unsigned* __restrict__ packed,
                                                     const int* __restrict__ bcnt,
                                                     int* __restrict__ pcnt,
                                                     int* __restrict__ deg,
                                                     int* __restrict__ pbt, int N) {
  __shared__ int hist[256];
  __shared__ int red[256];
  const int b = blockIdx.x, t = threadIdx.x;
  hist[t] = 0;
  __syncthreads();
  const int ecnt = min(bcnt[b], BCAP);
  const unsigned* pk = packed + (size_t)b * BCAP;
  for (int i = t; i < ecnt; i += 256) atomicAdd(&hist[pk[i] & 255u], 1);
  __syncthreads();
  int c = hist[t];
  int node = b * 256 + t;
  int pc = (node < N) ? ((c + 3) & ~3) : 0;
  if (node < N) { deg[node] = c; pcnt[node] = pc; }
  red[t] = pc;
  __syncthreads();
  for (int d = 128; d > 0; d >>= 1) {
    if (t < d) red[t] += red[t + d];
    __syncthreads();
  }
  if (t == 0) pbt[b] = red[0];
}

// bscan: exclusive scan of padded bucket totals -> bucket bases; offs[N] = total.
__global__ __launch_bounds__(512) void bscan_kernel(const int* __restrict__ pbt,
                                                    int* __restrict__ bbase,
                                                    int* __restrict__ offs, int N) {
  __shared__ int tmp[512];
  int t = threadIdx.x;
  int v = (t < NBUCK) ? pbt[t] : 0;
  int x = v;
  tmp[t] = x;
  __syncthreads();
  for (int d = 1; d < 512; d <<= 1) {
    int y = (t >= d) ? tmp[t - d] : 0;
    __syncthreads();
    x += y;
    tmp[t] = x;
    __syncthreads();
  }
  if (t < NBUCK) bbase[t] = x - v;
  if (t == NBUCK - 1) offs[N] = x;
}

// partBs: per-node padded scan -> offs; scatter edges; fill pad slots with sentinel N.
__global__ __launch_bounds__(256) void partBs_kernel(const unsigned* __restrict__ packed,
                                                     const int* __restrict__ bcnt,
                                                     const int* __restrict__ bbase,
                                                     const int* __restrict__ pcnt,
                                                     const int* __restrict__ deg,
                                                     int* __restrict__ offs,
                                                     int* __restrict__ ssrc, int N) {
  __shared__ int scanbuf[256];
  __shared__ int curs[256];
  const int b = blockIdx.x, t = threadIdx.x;
  const int node = b * 256 + t;
  int pc = (node < N) ? pcnt[node] : 0;
  int c  = (node < N) ? deg[node] : 0;
  int x = pc;
  scanbuf[t] = x;
  __syncthreads();
  for (int d = 1; d < 256; d <<= 1) {
    int y = (t >= d) ? scanbuf[t - d] : 0;
    __syncthreads();
    x += y;
    scanbuf[t] = x;
    __syncthreads();
  }
  int excl = x - pc;
  const int obase = bbase[b];
  if (node < N) offs[node] = obase + excl;
  curs[t] = excl;
  __syncthreads();

  const int ecnt = min(bcnt[b], BCAP);
  const unsigned* pk = packed + (size_t)b * BCAP;
  for (int i = t; i < ecnt; i += 256) {
    unsigned p = pk[i];
    int r = atomicAdd(&curs[p & 255u], 1);
    ssrc[obase + r] = (int)(p >> 8);
  }
  // pad slots -> sentinel row N (disjoint from scattered region per node)
  for (int j = c; j < pc; ++j) ssrc[obase + excl + j] = N;
}

// -------- weight swizzle: W[128][256] (=[Wl|Wr]) -> MFMA B-fragment order --------

__global__ __launch_bounds__(256) void wswz_kernel(const float* __restrict__ Wl1,
                                                   const float* __restrict__ Wr1,
                                                   const float* __restrict__ Wl2,
                                                   const float* __restrict__ Wr2,
                                                   __bf16* __restrict__ W1out,
                                                   __bf16* __restrict__ W2out) {
  int gi = blockIdx.x * blockDim.x + threadIdx.x;  // 0..65535
  bool L2 = gi >= 32768;
  int i = gi & 32767;
  int j = i & 7;
  int lane = (i >> 3) & 63;
  int c = (i >> 9) & 3;
  int tile = i >> 11;
  int k = c * 32 + ((lane >> 4) * 8) + j;
  int krow = L2 ? (((k & 7) << 4) | (k >> 3)) : k;
  int col = tile * 16 + (lane & 15);
  const float* Wl = L2 ? Wl2 : Wl1;
  const float* Wr = L2 ? Wr2 : Wr1;
  float v = (col < 128) ? Wl[krow * 128 + col] : Wr[krow * 128 + (col - 128)];
  (L2 ? W2out : W1out)[i] = (__bf16)v;
}

// ---------------- fused GEMM: [P | R] = A @ [Wl | Wr] (+bias on R) ----------------

template <bool A_IS_F32>
__global__ __launch_bounds__(256) void gemm_kernel(const void* __restrict__ Aptr,
                                                   const __bf16* __restrict__ Wswz,
                                                   const float* __restrict__ bias,
                                                   unsigned char* __restrict__ P,
                                                   __bf16* __restrict__ R, int M) {
  __shared__ __bf16 ldsA[64][136];
  const int t = threadIdx.x;
  const int m0 = blockIdx.x * 64;

  if (A_IS_F32) {
    const float* A = (const float*)Aptr;
#pragma unroll
    for (int it = 0; it < 8; ++it) {
      int row = it * 8 + (t >> 5);
      int col = (t & 31) * 4;
      float4 v = make_float4(0.f, 0.f, 0.f, 0.f);
      if (m0 + row < M) v = *(const float4*)&A[(size_t)(m0 + row) * 128 + col];
      bf16x4 bv;
      bv.x = (__bf16)v.x; bv.y = (__bf16)v.y; bv.z = (__bf16)v.z; bv.w = (__bf16)v.w;
      *(bf16x4*)&ldsA[row][col] = bv;
    }
  } else {
    const __bf16* A = (const __bf16*)Aptr;
#pragma unroll
    for (int it = 0; it < 4; ++it) {
      int row = it * 16 + (t >> 4);
      int col = (t & 15) * 8;
      uint4 v = make_uint4(0u, 0u, 0u, 0u);
      if (m0 + row < M) v = *(const uint4*)&A[(size_t)(m0 + row) * 128 + col];
      *(uint4*)&ldsA[row][col] = v;
    }
  }

  const int lane = t & 63;
  const int w = t >> 6;
  const int q = lane >> 4;
  const int s = lane & 15;

  float breg[8];
#pragma unroll
  for (int j = 0; j < 8; ++j) breg[j] = bias[j * 16 + s];

  __syncthreads();

  f32x4 acc[16];
  f32x4 zero = {0.f, 0.f, 0.f, 0.f};
#pragma unroll
  for (int i = 0; i < 16; ++i) acc[i] = zero;

  const __bf16* arow = &ldsA[w * 16 + s][0];
#pragma unroll
  for (int c = 0; c < 4; ++c) {
    bf16x8 a = *(const bf16x8*)&arow[c * 32 + q * 8];
#pragma unroll
    for (int nt = 0; nt < 16; ++nt) {
      bf16x8 b = *(const bf16x8*)&Wswz[(size_t)(((nt * 4 + c) * 64) + lane) * 8];
      acc[nt] = __builtin_amdgcn_mfma_f32_16x16x32_bf16(a, b, acc[nt], 0, 0, 0);
    }
  }

  const int rbase = m0 + w * 16 + q * 4;
#pragma unroll
  for (int r = 0; r < 4; ++r) {
    int row = rbase + r;
    if (row < M) {
      unsigned lo = 0, hi = 0;
      lo = __builtin_amdgcn_cvt_pk_fp8_f32(acc[0][r], acc[1][r], lo, false);
      lo = __builtin_amdgcn_cvt_pk_fp8_f32(acc[2][r], acc[3][r], lo, true);
      hi = __builtin_amdgcn_cvt_pk_fp8_f32(acc[4][r], acc[5][r], hi, false);
      hi = __builtin_amdgcn_cvt_pk_fp8_f32(acc[6][r], acc[7][r], hi, true);
      uint2 pv; pv.x = lo; pv.y = hi;
      *(uint2*)&P[(size_t)row * 128 + s * 8] = pv;

      bf16x8 o;
#pragma unroll
      for (int j = 0; j < 8; ++j) o[j] = (__bf16)(acc[8 + j][r] + breg[j]);
      *(bf16x8*)&R[(size_t)row * 128 + s * 8] = o;
    }
  }
}

// ------------- aggregation: H = relu(mean_agg(P) + R); FINAL fuses heads -------------
// 4 nodes per wave (one per 16-lane group). Padded+sentinel edge lists: branch-free
// gather, aligned dwordx4 ssrc loads, no cross-group reduce, all-lane stores.

template <bool FINAL>
__global__ __launch_bounds__(256) void agg_kernel(
    const unsigned char* __restrict__ P, const __bf16* R,
    const int* __restrict__ offs, const int* __restrict__ deg,
    const int* __restrict__ ssrc,
    __bf16* H, float* __restrict__ out,
    const float* __restrict__ Wp, const float* __restrict__ Wd,
    const float* __restrict__ bp, const float* __restrict__ bd, int n) {
  int w4 = (int)((blockIdx.x * blockDim.x + threadIdx.x) >> 6);
  int lane = threadIdx.x & 63;
  int g = lane >> 4;
  int s = lane & 15;
  int node = w4 * 4 + g;
  int nc = min(node, n - 1);
  int start = offs[nc];
  int pend = offs[nc + 1];

  f32x2 a01 = {0.f, 0.f}, a23 = {0.f, 0.f}, a45 = {0.f, 0.f}, a67 = {0.f, 0.f};

  const unsigned char* Pb = P + (size_t)s * 8;
  for (int cur = start; cur < pend; cur += 4) {
    uint4 sv = *(const uint4*)&ssrc[cur];   // 16B-aligned (padded segments)
    uint2 v0 = *(const uint2*)(Pb + (size_t)sv.x * 128);
    uint2 v1 = *(const uint2*)(Pb + (size_t)sv.y * 128);
    uint2 v2 = *(const uint2*)(Pb + (size_t)sv.z * 128);
    uint2 v3 = *(const uint2*)(Pb + (size_t)sv.w * 128);
    a01 += __builtin_amdgcn_cvt_pk_f32_fp8(v0.x, false);
    a23 += __builtin_amdgcn_cvt_pk_f32_fp8(v0.x, true);
    a45 += __builtin_amdgcn_cvt_pk_f32_fp8(v0.y, false);
    a67 += __builtin_amdgcn_cvt_pk_f32_fp8(v0.y, true);
    a01 += __builtin_amdgcn_cvt_pk_f32_fp8(v1.x, false);
    a23 += __builtin_amdgcn_cvt_pk_f32_fp8(v1.x, true);
    a45 += __builtin_amdgcn_cvt_pk_f32_fp8(v1.y, false);
    a67 += __builtin_amdgcn_cvt_pk_f32_fp8(v1.y, true);
    a01 += __builtin_amdgcn_cvt_pk_f32_fp8(v2.x, false);
    a23 += __builtin_amdgcn_cvt_pk_f32_fp8(v2.x, true);
    a45 += __builtin_amdgcn_cvt_pk_f32_fp8(v2.y, false);
    a67 += __builtin_amdgcn_cvt_pk_f32_fp8(v2.y, true);
    a01 += __builtin_amdgcn_cvt_pk_f32_fp8(v3.x, false);
    a23 += __builtin_amdgcn_cvt_pk_f32_fp8(v3.x, true);
    a45 += __builtin_amdgcn_cvt_pk_f32_fp8(v3.y, false);
    a67 += __builtin_amdgcn_cvt_pk_f32_fp8(v3.y, true);
  }

  int dg = deg[nc];
  float inv = 1.0f / (float)(dg > 0 ? dg : 1);

  bf16x8 rv = *(const bf16x8*)&R[(size_t)nc * 128 + s * 8];
  float acc[8] = {a01[0], a01[1], a23[0], a23[1], a45[0], a45[1], a67[0], a67[1]};
  float h[8];
#pragma unroll
  for (int j = 0; j < 8; ++j) {
    h[j] = fmaxf(acc[j] * inv + (float)rv[j], 0.f);
  }

  if (!FINAL) {
    if (node < n) {
      bf16x8 o;
#pragma unroll
      for (int j = 0; j < 8; ++j) o[j] = (__bf16)h[j];
      *(bf16x8*)&H[(size_t)node * 128 + s * 8] = o;
    }
  } else {
    float p = 0.f, dd = 0.f;
#pragma unroll
    for (int j = 0; j < 8; ++j) {
      p += h[j] * Wp[j * 16 + s];
      dd += h[j] * Wd[j * 16 + s];
    }
    p += __shfl_xor(p, 1, 64);  p += __shfl_xor(p, 2, 64);
    p += __shfl_xor(p, 4, 64);  p += __shfl_xor(p, 8, 64);
    dd += __shfl_xor(dd, 1, 64); dd += __shfl_xor(dd, 2, 64);
    dd += __shfl_xor(dd, 4, 64); dd += __shfl_xor(dd, 8, 64);
    if (node < n && s == 0) {
      float preds = p + bp[0];
      float sg = 1.0f / (1.0f + __expf(-(dd + bd[0])));
      out[node] = preds - sg;
      out[n + node] = preds + sg;
    }
  }
}

// ----------------------------------- launch -----------------------------------

extern "C" void kernel_launch(void* const* d_in, const int* in_sizes, int n_in,
                              void* d_out, int out_size, void* d_ws, size_t ws_size,
                              hipStream_t stream) {
  const float* x    = (const float*)d_in[0];
  const int*   ei   = (const int*)d_in[1];
  const float* Wl1 = (const float*)d_in[2];
  const float* Wr1 = (const float*)d_in[3];
  const float* b1  = (const float*)d_in[4];
  const float* Wl2 = (const float*)d_in[5];
  const float* Wr2 = (const float*)d_in[6];
  const float* b2  = (const float*)d_in[7];
  const float* Wp  = (const float*)d_in[8];
  const float* bp  = (const float*)d_in[9];
  const float* Wd  = (const float*)d_in[10];
  const float* bd  = (const float*)d_in[11];
  float* out = (float*)d_out;

  const int N = N_NODES, E = N_EDGES;
  const int* src = ei;
  const int* dst = ei + E;
  const size_t PADE = (size_t)E + 3 * (size_t)N + 64;  // padded edge capacity

  char* w = (char*)d_ws;
  unsigned char* P = (unsigned char*)w; w += (size_t)(N + 1) * 128;  // fp8, +sentinel row
  __bf16* Rbuf   = (__bf16*)w;   w += (size_t)N * 128 * 2;           // R1->H1->R2
  int* ssrc      = (int*)w;      w += PADE * 4;
  unsigned* pck  = (unsigned*)w; w += (size_t)NBUCK * BCAP * 4;      // 8.0 MB
  int* bcnt      = (int*)w;      w += 512 * 4;
  int* bbase     = (int*)w;      w += 512 * 4;
  int* pbt       = (int*)w;      w += 512 * 4;
  int* pcnt      = (int*)w;      w += (size_t)(N + 32) * 4;
  int* deg       = (int*)w;      w += (size_t)(N + 32) * 4;
  int* offs      = (int*)w;      w += (size_t)(N + 32) * 4;
  __bf16* Ws1    = (__bf16*)w;   w += 65536;
  __bf16* Ws2    = (__bf16*)w;   w += 65536;

  // graph preprocessing (shared by both layers)
  zerob_kernel<<<1, 512, 0, stream>>>(bcnt, (int*)(P + (size_t)N * 128));
  wswz_kernel<<<256, 256, 0, stream>>>(Wl1, Wr1, Wl2, Wr2, Ws1, Ws2);
  partA_kernel<<<(E + ACHUNK - 1) / ACHUNK, 256, 0, stream>>>(src, dst, bcnt, pck, E);
  partBh_kernel<<<NBUCK, 256, 0, stream>>>(pck, bcnt, pcnt, deg, pbt, N);
  bscan_kernel<<<1, 512, 0, stream>>>(pbt, bbase, offs, N);
  partBs_kernel<<<NBUCK, 256, 0, stream>>>(pck, bcnt, bbase, pcnt, deg, offs, ssrc, N);

  const int GB = (N + 63) / 64;   // 1563
  const int AB = (N + 15) / 16;   // 6250 blocks, 4 nodes/wave, 4 waves/block
  // layer 1
  gemm_kernel<true><<<GB, 256, 0, stream>>>(x, Ws1, b1, P, Rbuf, N);
  agg_kernel<false><<<AB, 256, 0, stream>>>(P, Rbuf, offs, deg, ssrc, Rbuf, nullptr,
                                            nullptr, nullptr, nullptr, nullptr, N);
  // layer 2 + fused heads
  gemm_kernel<false><<<GB, 256, 0, stream>>>(Rbuf, Ws2, b2, P, Rbuf, N);
  agg_kernel<true><<<AB, 256, 0, stream>>>(P, Rbuf, offs, deg, ssrc, nullptr, out,
                                           Wp, Wd, bp, bd, N);
}